// Round 10
// baseline (151.121 us; speedup 1.0000x reference)
//
#include <hip/hip_runtime.h>
#include <hip/hip_bf16.h>

// B=8, L=512, D=1024, H=16, HD=64
#define BB 8
#define LL 512
#define DD 1024
#define HH 16
#define HD 64
#define LOG2E 1.4426950408889634f

typedef __attribute__((ext_vector_type(8))) unsigned short u16x8;
typedef __attribute__((ext_vector_type(4))) unsigned short u16x4;
typedef __attribute__((ext_vector_type(8))) __bf16 bf16x8;
typedef __attribute__((ext_vector_type(4))) float f32x4;
typedef __attribute__((ext_vector_type(16))) float f32x16;

#define DEV __device__ __forceinline__

DEV unsigned short f2bf(float f) {               // native v_cvt (RNE)
    return __builtin_bit_cast(unsigned short, (__bf16)f);
}
DEV f32x4 mfma16(u16x8 a, u16x8 b, f32x4 c) {
    return __builtin_amdgcn_mfma_f32_16x16x32_bf16(
        __builtin_bit_cast(bf16x8, a), __builtin_bit_cast(bf16x8, b), c, 0, 0, 0);
}
DEV f32x16 mfma32(u16x8 a, u16x8 b, f32x16 c) {
    return __builtin_amdgcn_mfma_f32_32x32x16_bf16(
        __builtin_bit_cast(bf16x8, a), __builtin_bit_cast(bf16x8, b), c, 0, 0, 0);
}
// async global->LDS, 16B per lane; LDS dest = wave-uniform base + lane*16
typedef __attribute__((address_space(1))) void gv_t;
typedef __attribute__((address_space(3))) void lv_t;
DEV void gload16(const void* g, void* l) {
    __builtin_amdgcn_global_load_lds((gv_t*)g, (lv_t*)l, 16, 0, 0);
}

// Frag-major layouts (so every attn load is base + lane*16B, coalesced):
//  Q/K:  X[bh][tile=i>>5][ks=hd>>4][l=hi*32+lq][j]  elem = T[i][hd],
//        hi=(hd>>3)&1, j=hd&7, lq=i&31
//  QP/KP: same but outer index h
//  V:    V[bh][tile][c=dblk*2+ps][l=hi*32+lq][j]   elem = V[i][hd]

// ------------------------------------------------- fp32 -> bf16 convert (x)
__global__ __launch_bounds__(256) void cvt_x(const float* __restrict__ in,
                                             unsigned short* __restrict__ out) {
    int i = blockIdx.x * 256 + threadIdx.x;   // 1M threads, 4 floats each
    f32x4 v = *(const f32x4*)(in + i * 4);
    u16x4 o;
    o[0] = f2bf(v[0]); o[1] = f2bf(v[1]); o[2] = f2bf(v[2]); o[3] = f2bf(v[3]);
    *(u16x4*)(out + i * 4) = o;
}

// ------------------------------------- transpose fp32 in -> bf16 out (RxC)
__global__ __launch_bounds__(256) void transpose_cvt(
    const float* __restrict__ in, unsigned short* __restrict__ out,
    int R, int C) {
    __shared__ unsigned short tile[32][33];
    int c0 = blockIdx.x * 32, r0 = blockIdx.y * 32;
    int tx = threadIdx.x & 31, ty = threadIdx.x >> 5;
#pragma unroll
    for (int i = 0; i < 32; i += 8)
        tile[ty + i][tx] = f2bf(in[(r0 + ty + i) * C + c0 + tx]);
    __syncthreads();
#pragma unroll
    for (int i = 0; i < 32; i += 8)
        out[(c0 + ty + i) * R + r0 + tx] = tile[tx][ty + i];
}

// ---------- pos GEMM (pe computed in-kernel): pe(512x64)@w(64x2048),
// scattered to frag-major qpx/kpx; qp pre-scaled by log2(e)
__global__ __launch_bounds__(256) void posg(
    const float* __restrict__ w, unsigned short* __restrict__ qpx,
    unsigned short* __restrict__ kpx) {
    __shared__ float peS[64][64];
    __shared__ float wS[64][32];
    int c0 = blockIdx.x * 32, i0 = blockIdx.y * 64;
    int t = threadIdx.x;
#pragma unroll
    for (int j = 0; j < 16; ++j) {
        int o = t + j * 256;                 // 4096 = 64 rows x 64 cols
        int ri = o >> 6, d = o & 63, dd = d & 31;
        float inv = expf((float)dd * -0.2971077539347156f);  // -ln(1e4)/31
        float ang = (float)(i0 + ri - 256) * inv;
        peS[ri][d] = (d < 32) ? sinf(ang) : cosf(ang);
    }
#pragma unroll
    for (int j = 0; j < 8; ++j) {
        int o = t + j * 256;
        wS[o >> 5][o & 31] = w[(o >> 5) * 2048 + c0 + (o & 31)];
    }
    __syncthreads();
#pragma unroll
    for (int j = 0; j < 8; ++j) {
        int o = t + j * 256;
        int row = o >> 5, col = o & 31;
        float acc = 0.0f;
#pragma unroll
        for (int k = 0; k < 64; ++k) acc += peS[row][k] * wS[k][col];
        int c = c0 + col, i = i0 + row;
        int qt = i >> 5, lq = i & 31;
        int cc = (c < 1024) ? c : (c - 1024);
        int h = cc >> 6, k = cc & 63;
        int ks = k >> 4, h2 = (k >> 3) & 1, jj = k & 7;
        unsigned idx = ((unsigned)(h * 4096 + qt * 256 + ks * 64 + h2 * 32 + lq)
                        << 3) + jj;
        if (c < 1024) qpx[idx] = f2bf(acc * LOG2E);
        else          kpx[idx] = f2bf(acc);
    }
}

// ---------------------------------------------------------------- GEMM
// C = A(MxK bf16 rm) x Bt(NxK bf16 rm)^T. BK=64 (half the barriers of BK=32),
// global_load_lds staging with PRE-SWIZZLED SOURCE (chunk ^= row&7; LDS dest
// stays linear per m104) and matching swizzled ds_read -> 2-way banks (free).
// MODE 0: scatter bf16 to frag-major q(*log2e), k, v. MODE 1: fp32 +bias.
template <int MODE>
__global__ __launch_bounds__(256) void gemm_bt(
    const unsigned short* __restrict__ A, const unsigned short* __restrict__ Bt,
    int M, int N, int K, int NBX, unsigned short* __restrict__ o0,
    unsigned short* __restrict__ o1, unsigned short* __restrict__ o2,
    float* __restrict__ fout, const float* __restrict__ bias) {
    __shared__ __align__(16) unsigned short As[128 * 64];   // 16KB
    __shared__ __align__(16) unsigned short Bs[128 * 64];   // 16KB
    int g = blockIdx.x;
    int swz = (g & 7) * (gridDim.x >> 3) + (g >> 3);   // XCD-contiguous chunks
    int bx = swz % NBX, by = swz / NBX;
    int m0 = by * 128, n0 = bx * 128;
    int t = threadIdx.x;
    int w = t >> 6, l = t & 63, lg = l >> 4, lc = l & 15;
    int wr = w >> 1, wc = w & 1;

    f32x4 acc[4][4] = {};

    // staging: wave w covers rows [w*32, w*32+32) via 4 gloads of 8 rows.
    // lane l -> row +(l>>3), source chunk pre-swizzled so LDS[row][c] holds
    // global chunk c ^ (row&7).
    int srow = w * 32 + (l >> 3);
    int schk = (l & 7) ^ ((l >> 3) & 7);
    const unsigned short* Ab = A + (m0 + srow) * K + schk * 8;
    const unsigned short* Bb = Bt + (n0 + srow) * K + schk * 8;
    unsigned short* dA = As + w * 2048;     // rows w*32.. ; lane*16B auto
    unsigned short* dB = Bs + w * 2048;
    int sw = lc & 7;                        // read-side row&7

    for (int k0 = 0; k0 < K; k0 += 64) {
        __syncthreads();                    // prev compute done; LDS reusable
#pragma unroll
        for (int c = 0; c < 4; ++c) {
            gload16(Ab + c * 8 * K + k0, dA + c * 512);
            gload16(Bb + c * 8 * K + k0, dB + c * 512);
        }
        __syncthreads();                    // drains vmcnt -> tiles resident
#pragma unroll
        for (int ks = 0; ks < 2; ++ks) {
            u16x8 af[4], bf[4];
#pragma unroll
            for (int mm = 0; mm < 4; ++mm)
                af[mm] = *(const u16x8*)&As[(wr * 64 + mm * 16 + lc) * 64 +
                                            (((ks * 4 + lg) ^ sw) << 3)];
#pragma unroll
            for (int nn = 0; nn < 4; ++nn)
                bf[nn] = *(const u16x8*)&Bs[(wc * 64 + nn * 16 + lc) * 64 +
                                            (((ks * 4 + lg) ^ sw) << 3)];
#pragma unroll
            for (int mm = 0; mm < 4; ++mm)
#pragma unroll
                for (int nn = 0; nn < 4; ++nn)
                    acc[mm][nn] = mfma16(af[mm], bf[nn], acc[mm][nn]);
        }
    }

#pragma unroll
    for (int mm = 0; mm < 4; ++mm)
#pragma unroll
        for (int nn = 0; nn < 4; ++nn)
#pragma unroll
            for (int r = 0; r < 4; ++r) {
                int row = m0 + wr * 64 + mm * 16 + lg * 4 + r;
                int col = n0 + wc * 64 + nn * 16 + lc;
                float v = acc[mm][nn][r];
                if (MODE == 0) {
                    int bb = row >> 9, i = row & 511;
                    int which = col >> 10, dd = col & 1023;
                    int hh = dd >> 6, hd = dd & 63;
                    int bh2 = bb * HH + hh;
                    int tl = i >> 5, io = i & 31;
                    if (which == 2) {       // V frag-major
                        int h2 = (io >> 2) & 1, ps = (io >> 4) & 1;
                        int j = (io & 3) | (((io >> 3) & 1) << 2);
                        int dblk = hd >> 5, lq = hd & 31;
                        unsigned idx = ((unsigned)(bh2 * 4096 + tl * 256 +
                                        (dblk * 2 + ps) * 64 + h2 * 32 + lq)
                                        << 3) + j;
                        o2[idx] = f2bf(v);
                    } else {                // Q/K frag-major
                        int ks = hd >> 4, h2 = (hd >> 3) & 1, j = hd & 7;
                        unsigned idx = ((unsigned)(bh2 * 4096 + tl * 256 +
                                        ks * 64 + h2 * 32 + io) << 3) + j;
                        if (which == 0) o0[idx] = f2bf(v * LOG2E);
                        else            o1[idx] = f2bf(v);
                    }
                } else {
                    fout[row * N + col] = v + bias[col];
                }
            }
}

// ---------------------------------------------------------------- attention
// Swapped-QK^T + 2-way key split, frag-major (coalesced) inputs. FULLY
// UNROLLED tile loop + early V-load issue: no barriers/LDS in the loop, so
// the scheduler can hoist tile t+1 loads into tile t softmax (reg pipeline).
// No launch_bounds cap: spend VGPRs on ILP (r8 proved occupancy is not the
// limiter here).
__global__ void attn_k(
    const unsigned short* __restrict__ Qx, const unsigned short* __restrict__ Kx,
    const unsigned short* __restrict__ Vx, const unsigned short* __restrict__ QPx,
    const unsigned short* __restrict__ KPx, const int* __restrict__ mask,
    const int* __restrict__ qmask, const float* __restrict__ shp,
    unsigned short* __restrict__ out) {
    __shared__ float mbuf[2][64];
    __shared__ float lsbuf[2][64];
    __shared__ float obuf[2][64][33];          // +1 pad: conflict-free

    int g = blockIdx.x;                        // 1024 blocks
    int bid = ((g & 7) << 7) + (g >> 3);       // one batch per XCD
    int b = bid >> 7, h = (bid >> 3) & 15, qc = bid & 7;
    int t = threadIdx.x, w = t >> 6, l = t & 63;
    int qg = w & 1, kh = w >> 1;               // q-group, key-half
    int lq = l & 31, hi = l >> 5;
    int q = qc * 64 + qg * 32 + lq;            // this lane's q-row
    int bh = b * HH + h;
    int qt = qc * 2 + qg;                      // q 32-tile index

    // coalesced frag-major prologue loads (lane l -> +l*16B)
    const unsigned short* qb  = Qx  + (((unsigned)(bh * 4096 + qt * 256)) << 3) + (l << 3);
    const unsigned short* qpb = QPx + (((unsigned)(h  * 4096 + qt * 256)) << 3) + (l << 3);
    u16x8 qf[4], pf[4];
#pragma unroll
    for (int ks = 0; ks < 4; ++ks) {
        qf[ks] = *(const u16x8*)(qb + ks * 512);
        pf[ks] = *(const u16x8*)(qpb + ks * 512);
    }

    // ballot-packed key masks for THIS key half (256 bits, wave-uniform)
    unsigned long long km[4], qm[4];
#pragma unroll
    for (int t8 = 0; t8 < 4; ++t8) {
        int base = b * LL + (kh * 4 + t8) * 64 + l;
        km[t8] = __ballot(mask[base] != 0);
        qm[t8] = __ballot(qmask[base] != 0);
    }
    int qi = (qmask[b * LL + q] != 0) ? 1 : 0;

    const float M0 = -1.0e30f, NEGF = -3.0e38f, THR = 8.0f;
    float negs = -(*shp) * LOG2E;
    float m = M0, ls = 0.0f;
    f32x16 o0 = {}, o1 = {};
    float fq = (float)(q - 4 * hi);

#pragma unroll
    for (int tt = 0; tt < 8; ++tt) {
        int ttg = kh * 8 + tt;                 // global 32-key tile index
        // ---- issue ALL of this tile's loads first (K, KP, V coalesced)
        const unsigned short* kb  = Kx  + (((unsigned)(bh * 4096 + ttg * 256)) << 3) + (l << 3);
        const unsigned short* kpb = KPx + (((unsigned)(h  * 4096 + ttg * 256)) << 3) + (l << 3);
        const unsigned short* vb  = Vx  + (((unsigned)(bh * 4096 + ttg * 256)) << 3) + (l << 3);
        u16x8 vf0 = *(const u16x8*)(vb);
        u16x8 vf1 = *(const u16x8*)(vb + 512);
        u16x8 vf2 = *(const u16x8*)(vb + 1024);
        u16x8 vf3 = *(const u16x8*)(vb + 1536);
        // ---- S^T tile: two independent 4-deep MFMA chains
        f32x16 sk = {}, sp = {};
#pragma unroll
        for (int ks = 0; ks < 4; ++ks) {
            sk = mfma32(*(const u16x8*)(kb + ks * 512), qf[ks], sk);
            sp = mfma32(*(const u16x8*)(kpb + ks * 512), pf[ks], sp);
        }

        // ---- masks + gaussian (log2 domain)
        unsigned kwn = ((unsigned)(km[tt >> 1] >> ((tt & 1) * 32))) >> (hi * 4);
        unsigned qwn = ((unsigned)(qm[tt >> 1] >> ((tt & 1) * 32))) >> (hi * 4);
        float bt = fq - 32.0f * (float)ttg;
        float p[16];
#pragma unroll
        for (int r = 0; r < 16; ++r) {
            const int off = (r & 3) + 8 * (r >> 2);   // key row within tile
            float v = sk[r] + sp[r];
            v = (((qwn >> off) & 1u) == (unsigned)qi) ? v : 0.0f;
            float dr = bt - (float)off;
            v = __builtin_fmaf(negs * dr, dr, v);
            v = ((kwn >> off) & 1u) ? v : NEGF;
            p[r] = v;
        }
        // ---- row max over tile (in-lane tree + cross-half shfl)
        float a0 = fmaxf(fmaxf(p[0], p[1]), fmaxf(p[2], p[3]));
        float a1 = fmaxf(fmaxf(p[4], p[5]), fmaxf(p[6], p[7]));
        float a2 = fmaxf(fmaxf(p[8], p[9]), fmaxf(p[10], p[11]));
        float a3 = fmaxf(fmaxf(p[12], p[13]), fmaxf(p[14], p[15]));
        float pmax = fmaxf(fmaxf(a0, a1), fmaxf(a2, a3));
        pmax = fmaxf(pmax, __shfl_xor(pmax, 32));
        // ---- defer-max rescale (wave-uniform branch, per-lane m)
        if (!__all(pmax <= m + THR)) {
            float mn = fmaxf(m, pmax);
            float sc = __builtin_amdgcn_exp2f(m - mn);
#pragma unroll
            for (int r = 0; r < 16; ++r) { o0[r] *= sc; o1[r] *= sc; }
            ls *= sc;
            m = mn;
        }
        // ---- P = exp2(s - m) (<= 2^THR), partial row-sum
#pragma unroll
        for (int r = 0; r < 16; ++r) p[r] = __builtin_amdgcn_exp2f(p[r] - m);
        ls += (((p[0] + p[1]) + (p[2] + p[3])) + ((p[4] + p[5]) + (p[6] + p[7]))) +
              (((p[8] + p[9]) + (p[10] + p[11])) +
               ((p[12] + p[13]) + (p[14] + p[15])));
        // ---- PV slot-paired with frag-major V
        u16x8 pf0, pf1;
#pragma unroll
        for (int j = 0; j < 8; ++j) { pf0[j] = f2bf(p[j]); pf1[j] = f2bf(p[8 + j]); }
        o0 = mfma32(vf0, pf0, o0);
        o0 = mfma32(vf1, pf1, o0);
        o1 = mfma32(vf2, pf0, o1);
        o1 = mfma32(vf3, pf1, o1);
    }

    // ---- flash-combine the two key halves via LDS
    if (kh == 1) {
        mbuf[qg][l] = m;
        lsbuf[qg][l] = ls;
#pragma unroll
        for (int r = 0; r < 16; ++r) {
            obuf[qg][l][r] = o0[r];
            obuf[qg][l][16 + r] = o1[r];
        }
    }
    __syncthreads();
    if (kh == 0) {
        float m1 = mbuf[qg][l], ls1 = lsbuf[qg][l];
        float mm = fmaxf(m, m1);
        float sc0 = __builtin_amdgcn_exp2f(m - mm);
        float sc1 = __builtin_amdgcn_exp2f(m1 - mm);
        float lsm = ls * sc0 + ls1 * sc1;
        float rs = lsm + __shfl_xor(lsm, 32);
        float rinv = __builtin_amdgcn_rcpf(rs);       // rs >= 1
        unsigned short* ob = out + ((long)(b * LL + q)) * DD + h * HD + hi * 4;
#pragma unroll
        for (int rg = 0; rg < 4; ++rg) {
            u16x4 pk0, pk1;
#pragma unroll
            for (int rr = 0; rr < 4; ++rr) {
                int i = rg * 4 + rr;
                float v0 = __builtin_fmaf(o0[i], sc0, obuf[qg][l][i] * sc1);
                float v1 = __builtin_fmaf(o1[i], sc0, obuf[qg][l][16 + i] * sc1);
                pk0[rr] = f2bf(v0 * rinv);            // d = hi*4 + rg*8 + rr
                pk1[rr] = f2bf(v1 * rinv);
            }
            *(u16x4*)(ob + rg * 8) = pk0;
            *(u16x4*)(ob + 32 + rg * 8) = pk1;
        }
    }
}

// ---------------------------------------------------------------- launch
extern "C" void kernel_launch(void* const* d_in, const int* in_sizes, int n_in,
                              void* d_out, int out_size, void* d_ws,
                              size_t ws_size, hipStream_t stream) {
    const float* x     = (const float*)d_in[0];
    const int*   mask  = (const int*)d_in[1];
    const int*   qmask = (const int*)d_in[2];
    const float* w_qkv = (const float*)d_in[3];
    const float* w_qkp = (const float*)d_in[4];
    const float* w_fc  = (const float*)d_in[5];
    const float* b_fc  = (const float*)d_in[6];
    const float* shift = (const float*)d_in[7];
    // d_in[8] (bias) cancels in softmax — unused

    char* ws = (char*)d_ws;
    unsigned short* xb   = (unsigned short*)(ws);              //  8 MB
    unsigned short* qb   = (unsigned short*)(ws + 8388608);    //  8 MB frag-major Q
    unsigned short* kb   = (unsigned short*)(ws + 16777216);   //  8 MB frag-major K
    unsigned short* vtb  = (unsigned short*)(ws + 25165824);   //  8 MB frag-major V
    unsigned short* qp   = (unsigned short*)(ws + 33554432);   //  1 MB frag-major QP
    unsigned short* kp   = (unsigned short*)(ws + 34603008);   //  1 MB frag-major KP
    unsigned short* wqt  = (unsigned short*)(ws + 35651584);   //  6 MB (3D,D)
    unsigned short* wft  = (unsigned short*)(ws + 41943040);   //  2 MB (D,D)
    unsigned short* aout = (unsigned short*)(ws + 44040192);   //  8 MB (B,L,D)

    cvt_x<<<4096, 256, 0, stream>>>(x, xb);
    transpose_cvt<<<dim3(96, 32), 256, 0, stream>>>(w_qkv, wqt, 1024, 3072);
    transpose_cvt<<<dim3(32, 32), 256, 0, stream>>>(w_fc, wft, 1024, 1024);
    posg<<<dim3(64, 8), 256, 0, stream>>>(w_qkp, qp, kp);
    gemm_bt<0><<<768, 256, 0, stream>>>(xb, wqt, 4096, 3072, 1024, 24, qb, kb,
                                        vtb, nullptr, nullptr);
    attn_k<<<1024, 256, 0, stream>>>(qb, kb, vtb, qp, kp, mask, qmask, shift,
                                     aout);
    gemm_bt<1><<<256, 256, 0, stream>>>(aout, wft, 4096, 1024, 1024, 8, nullptr,
                                        nullptr, nullptr, (float*)d_out, b_fc);
}

// Round 11
// 141.445 us; speedup vs baseline: 1.0684x; 1.0684x over previous
//
#include <hip/hip_runtime.h>
#include <hip/hip_bf16.h>

// B=8, L=512, D=1024, H=16, HD=64
#define BB 8
#define LL 512
#define DD 1024
#define HH 16
#define HD 64
#define LOG2E 1.4426950408889634f

typedef __attribute__((ext_vector_type(8))) unsigned short u16x8;
typedef __attribute__((ext_vector_type(4))) unsigned short u16x4;
typedef __attribute__((ext_vector_type(8))) __bf16 bf16x8;
typedef __attribute__((ext_vector_type(4))) float f32x4;
typedef __attribute__((ext_vector_type(16))) float f32x16;

#define DEV __device__ __forceinline__

DEV unsigned short f2bf(float f) {               // native v_cvt (RNE)
    return __builtin_bit_cast(unsigned short, (__bf16)f);
}
DEV f32x4 mfma16(u16x8 a, u16x8 b, f32x4 c) {
    return __builtin_amdgcn_mfma_f32_16x16x32_bf16(
        __builtin_bit_cast(bf16x8, a), __builtin_bit_cast(bf16x8, b), c, 0, 0, 0);
}
DEV f32x16 mfma32(u16x8 a, u16x8 b, f32x16 c) {
    return __builtin_amdgcn_mfma_f32_32x32x16_bf16(
        __builtin_bit_cast(bf16x8, a), __builtin_bit_cast(bf16x8, b), c, 0, 0, 0);
}
// async global->LDS, 16B per lane; LDS dest = wave-uniform base + lane*16
typedef __attribute__((address_space(1))) void gv_t;
typedef __attribute__((address_space(3))) void lv_t;
DEV void gload16(const void* g, void* l) {
    __builtin_amdgcn_global_load_lds((gv_t*)g, (lv_t*)l, 16, 0, 0);
}

// Frag-major layouts (so every attn load is base + lane*16B, coalesced):
//  Q/K:  X[bh][tile=i>>5][ks=hd>>4][l=hi*32+lq][j]  elem = T[i][hd]
//  QP/KP: same but outer index h
//  V:    V[bh][tile][c=dblk*2+ps][l][j]             elem = V[i][hd]

// ------------------------------------- transpose fp32 in -> bf16 out (RxC)
__global__ __launch_bounds__(256) void transpose_cvt(
    const float* __restrict__ in, unsigned short* __restrict__ out,
    int R, int C) {
    __shared__ unsigned short tile[32][33];
    int c0 = blockIdx.x * 32, r0 = blockIdx.y * 32;
    int tx = threadIdx.x & 31, ty = threadIdx.x >> 5;
#pragma unroll
    for (int i = 0; i < 32; i += 8)
        tile[ty + i][tx] = f2bf(in[(r0 + ty + i) * C + c0 + tx]);
    __syncthreads();
#pragma unroll
    for (int i = 0; i < 32; i += 8)
        out[(c0 + ty + i) * R + r0 + tx] = tile[tx][ty + i];
}

// ---------- pos GEMM (pe computed in-kernel): pe(512x64)@w(64x2048),
// scattered to frag-major qpx/kpx; qp pre-scaled by log2(e)
__global__ __launch_bounds__(256) void posg(
    const float* __restrict__ w, unsigned short* __restrict__ qpx,
    unsigned short* __restrict__ kpx) {
    __shared__ float peS[64][64];
    __shared__ float wS[64][32];
    int c0 = blockIdx.x * 32, i0 = blockIdx.y * 64;
    int t = threadIdx.x;
#pragma unroll
    for (int j = 0; j < 16; ++j) {
        int o = t + j * 256;                 // 4096 = 64 rows x 64 cols
        int ri = o >> 6, d = o & 63, dd = d & 31;
        float inv = expf((float)dd * -0.2971077539347156f);  // -ln(1e4)/31
        float ang = (float)(i0 + ri - 256) * inv;
        peS[ri][d] = (d < 32) ? sinf(ang) : cosf(ang);
    }
#pragma unroll
    for (int j = 0; j < 8; ++j) {
        int o = t + j * 256;
        wS[o >> 5][o & 31] = w[(o >> 5) * 2048 + c0 + (o & 31)];
    }
    __syncthreads();
#pragma unroll
    for (int j = 0; j < 8; ++j) {
        int o = t + j * 256;
        int row = o >> 5, col = o & 31;
        float acc = 0.0f;
#pragma unroll
        for (int k = 0; k < 64; ++k) acc += peS[row][k] * wS[k][col];
        int c = c0 + col, i = i0 + row;
        int qt = i >> 5, lq = i & 31;
        int cc = (c < 1024) ? c : (c - 1024);
        int h = cc >> 6, k = cc & 63;
        int ks = k >> 4, h2 = (k >> 3) & 1, jj = k & 7;
        unsigned idx = ((unsigned)(h * 4096 + qt * 256 + ks * 64 + h2 * 32 + lq)
                        << 3) + jj;
        if (c < 1024) qpx[idx] = f2bf(acc * LOG2E);
        else          kpx[idx] = f2bf(acc);
    }
}

// ---------------------------------------------------------------- GEMM
// C = A(MxK) x Bt(NxK bf16 rm)^T. BK=32 (r9 structure: 16KB LDS, occupancy
// intact). Bank-conflict swizzle: LDS[row][c] holds global chunk
// c ^ ((row>>1)&3) -- gload uses pre-swizzled SOURCE (dest linear, rule 21),
// ds_read XORs the same f(row); 16 lanes spread over 8 bank-groups = 2-way
// (free, m136). MODE 0: A is fp32 x, staged via regs + f2bf + ds_write
// (fused cvt_x, prefetch next iter's A regs under the barrier drain);
// scatter bf16 to frag-major q(*log2e), k, v. MODE 1: A bf16 via gload;
// fout = C + bias (fp32).
template <int MODE>
__global__ __launch_bounds__(256) void gemm_bt(
    const float* __restrict__ Af, const unsigned short* __restrict__ Abf,
    const unsigned short* __restrict__ Bt,
    int M, int N, int K, int NBX, unsigned short* __restrict__ o0,
    unsigned short* __restrict__ o1, unsigned short* __restrict__ o2,
    float* __restrict__ fout, const float* __restrict__ bias) {
    __shared__ __align__(16) unsigned short As[128 * 32];
    __shared__ __align__(16) unsigned short Bs[128 * 32];
    int g = blockIdx.x;
    int swz = (g & 7) * (gridDim.x >> 3) + (g >> 3);   // XCD-contiguous chunks
    int bx = swz % NBX, by = swz / NBX;
    int m0 = by * 128, n0 = bx * 128;
    int t = threadIdx.x;
    int w = t >> 6, l = t & 63, lg = l >> 4, lc = l & 15;
    int wr = w >> 1, wc = w & 1;

    f32x4 acc[4][4] = {};

    int sr = t >> 2;                        // staging row 0..63 (and +64)
    int sc = (t & 3) ^ ((t >> 3) & 3);      // swizzled chunk, f(row)=(row>>1)&3
    const unsigned short* Bb = Bt + (n0 + sr) * K + sc * 8;
    unsigned short* dB0 = Bs + w * 512;     // lane*16B -> row w*16+(l>>2)
    unsigned short* dB1 = Bs + 2048 + w * 512;

    // A path (MODE 0: fp32 regs; MODE 1: gload like B)
    const float* Axf = nullptr;
    const unsigned short* Ab = nullptr;
    unsigned short* dA0 = As + w * 512;
    unsigned short* dA1 = As + 2048 + w * 512;
    f32x4 pa00, pa01, pa10, pa11;           // prefetched A fp32 (2 rows x 8)
    if (MODE == 0) {
        Axf = Af + (m0 + sr) * K + (t & 3) * 8;
        pa00 = *(const f32x4*)(Axf);
        pa01 = *(const f32x4*)(Axf + 4);
        pa10 = *(const f32x4*)(Axf + 64 * K);
        pa11 = *(const f32x4*)(Axf + 64 * K + 4);
    } else {
        Ab = Abf + (m0 + sr) * K + sc * 8;
    }
    int wA0 = sr * 32 + sc * 8;             // swizzled ds_write dests
    int wA1 = (sr + 64) * 32 + sc * 8;
    int rsw = (lc >> 1) & 3;                // read-side f(row)

    for (int k0 = 0; k0 < K; k0 += 32) {
        __syncthreads();                    // prev compute done; LDS reusable
        if (MODE == 0) {
            u16x8 wv0, wv1;
#pragma unroll
            for (int j = 0; j < 4; ++j) {
                wv0[j] = f2bf(pa00[j]); wv0[4 + j] = f2bf(pa01[j]);
                wv1[j] = f2bf(pa10[j]); wv1[4 + j] = f2bf(pa11[j]);
            }
            *(u16x8*)&As[wA0] = wv0;
            *(u16x8*)&As[wA1] = wv1;
            gload16(Bb + k0, dB0);
            gload16(Bb + 64 * K + k0, dB1);
            if (k0 + 32 < K) {              // prefetch next iter's A regs
                pa00 = *(const f32x4*)(Axf + k0 + 32);
                pa01 = *(const f32x4*)(Axf + k0 + 36);
                pa10 = *(const f32x4*)(Axf + 64 * K + k0 + 32);
                pa11 = *(const f32x4*)(Axf + 64 * K + k0 + 36);
            }
        } else {
            gload16(Ab + k0, dA0);
            gload16(Ab + 64 * K + k0, dA1);
            gload16(Bb + k0, dB0);
            gload16(Bb + 64 * K + k0, dB1);
        }
        __syncthreads();                    // drains vm+lgkm -> tiles resident
        u16x8 af[4], bf[4];
#pragma unroll
        for (int mm = 0; mm < 4; ++mm)
            af[mm] = *(const u16x8*)&As[(wr * 64 + mm * 16 + lc) * 32 +
                                        ((lg ^ rsw) << 3)];
#pragma unroll
        for (int nn = 0; nn < 4; ++nn)
            bf[nn] = *(const u16x8*)&Bs[(wc * 64 + nn * 16 + lc) * 32 +
                                        ((lg ^ rsw) << 3)];
#pragma unroll
        for (int mm = 0; mm < 4; ++mm)
#pragma unroll
            for (int nn = 0; nn < 4; ++nn)
                acc[mm][nn] = mfma16(af[mm], bf[nn], acc[mm][nn]);
    }

#pragma unroll
    for (int mm = 0; mm < 4; ++mm)
#pragma unroll
        for (int nn = 0; nn < 4; ++nn)
#pragma unroll
            for (int r = 0; r < 4; ++r) {
                int row = m0 + wr * 64 + mm * 16 + lg * 4 + r;
                int col = n0 + wc * 64 + nn * 16 + lc;
                float v = acc[mm][nn][r];
                if (MODE == 0) {
                    int bb = row >> 9, i = row & 511;
                    int which = col >> 10, dd = col & 1023;
                    int hh = dd >> 6, hd = dd & 63;
                    int bh2 = bb * HH + hh;
                    int tl = i >> 5, io = i & 31;
                    if (which == 2) {       // V frag-major
                        int h2 = (io >> 2) & 1, ps = (io >> 4) & 1;
                        int j = (io & 3) | (((io >> 3) & 1) << 2);
                        int dblk = hd >> 5, lq = hd & 31;
                        unsigned idx = ((unsigned)(bh2 * 4096 + tl * 256 +
                                        (dblk * 2 + ps) * 64 + h2 * 32 + lq)
                                        << 3) + j;
                        o2[idx] = f2bf(v);
                    } else {                // Q/K frag-major
                        int ks = hd >> 4, h2 = (hd >> 3) & 1, j = hd & 7;
                        unsigned idx = ((unsigned)(bh2 * 4096 + tl * 256 +
                                        ks * 64 + h2 * 32 + io) << 3) + j;
                        if (which == 0) o0[idx] = f2bf(v * LOG2E);
                        else            o1[idx] = f2bf(v);
                    }
                } else {
                    fout[row * N + col] = v + bias[col];
                }
            }
}

// ---------------------------------------------------------------- attention
// Swapped-QK^T + 2-way key split, frag-major (coalesced) inputs. Fully
// unrolled tile loop, early V-load issue, no barriers/LDS in the loop.
__global__ void attn_k(
    const unsigned short* __restrict__ Qx, const unsigned short* __restrict__ Kx,
    const unsigned short* __restrict__ Vx, const unsigned short* __restrict__ QPx,
    const unsigned short* __restrict__ KPx, const int* __restrict__ mask,
    const int* __restrict__ qmask, const float* __restrict__ shp,
    unsigned short* __restrict__ out) {
    __shared__ float mbuf[2][64];
    __shared__ float lsbuf[2][64];
    __shared__ float obuf[2][64][33];          // +1 pad: conflict-free

    int g = blockIdx.x;                        // 1024 blocks
    int bid = ((g & 7) << 7) + (g >> 3);       // one batch per XCD
    int b = bid >> 7, h = (bid >> 3) & 15, qc = bid & 7;
    int t = threadIdx.x, w = t >> 6, l = t & 63;
    int qg = w & 1, kh = w >> 1;               // q-group, key-half
    int lq = l & 31, hi = l >> 5;
    int q = qc * 64 + qg * 32 + lq;            // this lane's q-row
    int bh = b * HH + h;
    int qt = qc * 2 + qg;                      // q 32-tile index

    // coalesced frag-major prologue loads (lane l -> +l*16B)
    const unsigned short* qb  = Qx  + (((unsigned)(bh * 4096 + qt * 256)) << 3) + (l << 3);
    const unsigned short* qpb = QPx + (((unsigned)(h  * 4096 + qt * 256)) << 3) + (l << 3);
    u16x8 qf[4], pf[4];
#pragma unroll
    for (int ks = 0; ks < 4; ++ks) {
        qf[ks] = *(const u16x8*)(qb + ks * 512);
        pf[ks] = *(const u16x8*)(qpb + ks * 512);
    }

    // ballot-packed key masks for THIS key half (256 bits, wave-uniform)
    unsigned long long km[4], qm[4];
#pragma unroll
    for (int t8 = 0; t8 < 4; ++t8) {
        int base = b * LL + (kh * 4 + t8) * 64 + l;
        km[t8] = __ballot(mask[base] != 0);
        qm[t8] = __ballot(qmask[base] != 0);
    }
    int qi = (qmask[b * LL + q] != 0) ? 1 : 0;

    const float M0 = -1.0e30f, NEGF = -3.0e38f, THR = 8.0f;
    float negs = -(*shp) * LOG2E;
    float m = M0, ls = 0.0f;
    f32x16 o0 = {}, o1 = {};
    float fq = (float)(q - 4 * hi);

#pragma unroll
    for (int tt = 0; tt < 8; ++tt) {
        int ttg = kh * 8 + tt;                 // global 32-key tile index
        // ---- issue ALL of this tile's loads first (K, KP, V coalesced)
        const unsigned short* kb  = Kx  + (((unsigned)(bh * 4096 + ttg * 256)) << 3) + (l << 3);
        const unsigned short* kpb = KPx + (((unsigned)(h  * 4096 + ttg * 256)) << 3) + (l << 3);
        const unsigned short* vb  = Vx  + (((unsigned)(bh * 4096 + ttg * 256)) << 3) + (l << 3);
        u16x8 vf0 = *(const u16x8*)(vb);
        u16x8 vf1 = *(const u16x8*)(vb + 512);
        u16x8 vf2 = *(const u16x8*)(vb + 1024);
        u16x8 vf3 = *(const u16x8*)(vb + 1536);
        // ---- S^T tile: two independent 4-deep MFMA chains
        f32x16 sk = {}, sp = {};
#pragma unroll
        for (int ks = 0; ks < 4; ++ks) {
            sk = mfma32(*(const u16x8*)(kb + ks * 512), qf[ks], sk);
            sp = mfma32(*(const u16x8*)(kpb + ks * 512), pf[ks], sp);
        }

        // ---- masks + gaussian (log2 domain)
        unsigned kwn = ((unsigned)(km[tt >> 1] >> ((tt & 1) * 32))) >> (hi * 4);
        unsigned qwn = ((unsigned)(qm[tt >> 1] >> ((tt & 1) * 32))) >> (hi * 4);
        float bt = fq - 32.0f * (float)ttg;
        float p[16];
#pragma unroll
        for (int r = 0; r < 16; ++r) {
            const int off = (r & 3) + 8 * (r >> 2);   // key row within tile
            float v = sk[r] + sp[r];
            v = (((qwn >> off) & 1u) == (unsigned)qi) ? v : 0.0f;
            float dr = bt - (float)off;
            v = __builtin_fmaf(negs * dr, dr, v);
            v = ((kwn >> off) & 1u) ? v : NEGF;
            p[r] = v;
        }
        // ---- row max over tile (in-lane tree + cross-half shfl)
        float a0 = fmaxf(fmaxf(p[0], p[1]), fmaxf(p[2], p[3]));
        float a1 = fmaxf(fmaxf(p[4], p[5]), fmaxf(p[6], p[7]));
        float a2 = fmaxf(fmaxf(p[8], p[9]), fmaxf(p[10], p[11]));
        float a3 = fmaxf(fmaxf(p[12], p[13]), fmaxf(p[14], p[15]));
        float pmax = fmaxf(fmaxf(a0, a1), fmaxf(a2, a3));
        pmax = fmaxf(pmax, __shfl_xor(pmax, 32));
        // ---- defer-max rescale (wave-uniform branch, per-lane m)
        if (!__all(pmax <= m + THR)) {
            float mn = fmaxf(m, pmax);
            float sc = __builtin_amdgcn_exp2f(m - mn);
#pragma unroll
            for (int r = 0; r < 16; ++r) { o0[r] *= sc; o1[r] *= sc; }
            ls *= sc;
            m = mn;
        }
        // ---- P = exp2(s - m) (<= 2^THR), partial row-sum
#pragma unroll
        for (int r = 0; r < 16; ++r) p[r] = __builtin_amdgcn_exp2f(p[r] - m);
        ls += (((p[0] + p[1]) + (p[2] + p[3])) + ((p[4] + p[5]) + (p[6] + p[7]))) +
              (((p[8] + p[9]) + (p[10] + p[11])) +
               ((p[12] + p[13]) + (p[14] + p[15])));
        // ---- PV slot-paired with frag-major V
        u16x8 pf0, pf1;
#pragma unroll
        for (int j = 0; j < 8; ++j) { pf0[j] = f2bf(p[j]); pf1[j] = f2bf(p[8 + j]); }
        o0 = mfma32(vf0, pf0, o0);
        o0 = mfma32(vf1, pf1, o0);
        o1 = mfma32(vf2, pf0, o1);
        o1 = mfma32(vf3, pf1, o1);
    }

    // ---- flash-combine the two key halves via LDS
    if (kh == 1) {
        mbuf[qg][l] = m;
        lsbuf[qg][l] = ls;
#pragma unroll
        for (int r = 0; r < 16; ++r) {
            obuf[qg][l][r] = o0[r];
            obuf[qg][l][16 + r] = o1[r];
        }
    }
    __syncthreads();
    if (kh == 0) {
        float m1 = mbuf[qg][l], ls1 = lsbuf[qg][l];
        float mm = fmaxf(m, m1);
        float sc0 = __builtin_amdgcn_exp2f(m - mm);
        float sc1 = __builtin_amdgcn_exp2f(m1 - mm);
        float lsm = ls * sc0 + ls1 * sc1;
        float rs = lsm + __shfl_xor(lsm, 32);
        float rinv = __builtin_amdgcn_rcpf(rs);       // rs >= 1
        unsigned short* ob = out + ((long)(b * LL + q)) * DD + h * HD + hi * 4;
#pragma unroll
        for (int rg = 0; rg < 4; ++rg) {
            u16x4 pk0, pk1;
#pragma unroll
            for (int rr = 0; rr < 4; ++rr) {
                int i = rg * 4 + rr;
                float v0 = __builtin_fmaf(o0[i], sc0, obuf[qg][l][i] * sc1);
                float v1 = __builtin_fmaf(o1[i], sc0, obuf[qg][l][16 + i] * sc1);
                pk0[rr] = f2bf(v0 * rinv);            // d = hi*4 + rg*8 + rr
                pk1[rr] = f2bf(v1 * rinv);
            }
            *(u16x4*)(ob + rg * 8) = pk0;
            *(u16x4*)(ob + 32 + rg * 8) = pk1;
        }
    }
}

// ---------------------------------------------------------------- launch
extern "C" void kernel_launch(void* const* d_in, const int* in_sizes, int n_in,
                              void* d_out, int out_size, void* d_ws,
                              size_t ws_size, hipStream_t stream) {
    const float* x     = (const float*)d_in[0];
    const int*   mask  = (const int*)d_in[1];
    const int*   qmask = (const int*)d_in[2];
    const float* w_qkv = (const float*)d_in[3];
    const float* w_qkp = (const float*)d_in[4];
    const float* w_fc  = (const float*)d_in[5];
    const float* b_fc  = (const float*)d_in[6];
    const float* shift = (const float*)d_in[7];
    // d_in[8] (bias) cancels in softmax — unused

    char* ws = (char*)d_ws;
    unsigned short* qb   = (unsigned short*)(ws + 8388608);    //  8 MB frag-major Q
    unsigned short* kb   = (unsigned short*)(ws + 16777216);   //  8 MB frag-major K
    unsigned short* vtb  = (unsigned short*)(ws + 25165824);   //  8 MB frag-major V
    unsigned short* qp   = (unsigned short*)(ws + 33554432);   //  1 MB frag-major QP
    unsigned short* kp   = (unsigned short*)(ws + 34603008);   //  1 MB frag-major KP
    unsigned short* wqt  = (unsigned short*)(ws + 35651584);   //  6 MB (3D,D)
    unsigned short* wft  = (unsigned short*)(ws + 41943040);   //  2 MB (D,D)
    unsigned short* aout = (unsigned short*)(ws + 44040192);   //  8 MB (B,L,D)

    transpose_cvt<<<dim3(96, 32), 256, 0, stream>>>(w_qkv, wqt, 1024, 3072);
    transpose_cvt<<<dim3(32, 32), 256, 0, stream>>>(w_fc, wft, 1024, 1024);
    posg<<<dim3(64, 8), 256, 0, stream>>>(w_qkp, qp, kp);
    gemm_bt<0><<<768, 256, 0, stream>>>(x, nullptr, wqt, 4096, 3072, 1024, 24,
                                        qb, kb, vtb, nullptr, nullptr);
    attn_k<<<1024, 256, 0, stream>>>(qb, kb, vtb, qp, kp, mask, qmask, shift,
                                     aout);
    gemm_bt<1><<<256, 256, 0, stream>>>(nullptr, aout, wft, 4096, 1024, 1024, 8,
                                        nullptr, nullptr, nullptr,
                                        (float*)d_out, b_fc);
}

// Round 12
// 136.178 us; speedup vs baseline: 1.1097x; 1.0387x over previous
//
#include <hip/hip_runtime.h>
#include <hip/hip_bf16.h>

// B=8, L=512, D=1024, H=16, HD=64
#define BB 8
#define LL 512
#define DD 1024
#define HH 16
#define HD 64
#define LOG2E 1.4426950408889634f

typedef __attribute__((ext_vector_type(8))) unsigned short u16x8;
typedef __attribute__((ext_vector_type(4))) unsigned short u16x4;
typedef __attribute__((ext_vector_type(8))) __bf16 bf16x8;
typedef __attribute__((ext_vector_type(4))) float f32x4;
typedef __attribute__((ext_vector_type(16))) float f32x16;

#define DEV __device__ __forceinline__

DEV unsigned short f2bf(float f) {               // native v_cvt (RNE)
    return __builtin_bit_cast(unsigned short, (__bf16)f);
}
DEV f32x4 mfma16(u16x8 a, u16x8 b, f32x4 c) {
    return __builtin_amdgcn_mfma_f32_16x16x32_bf16(
        __builtin_bit_cast(bf16x8, a), __builtin_bit_cast(bf16x8, b), c, 0, 0, 0);
}
DEV f32x16 mfma32(u16x8 a, u16x8 b, f32x16 c) {
    return __builtin_amdgcn_mfma_f32_32x32x16_bf16(
        __builtin_bit_cast(bf16x8, a), __builtin_bit_cast(bf16x8, b), c, 0, 0, 0);
}
// async global->LDS, 16B per lane; LDS dest = wave-uniform base + lane*16
typedef __attribute__((address_space(1))) void gv_t;
typedef __attribute__((address_space(3))) void lv_t;
DEV void gload16(const void* g, void* l) {
    __builtin_amdgcn_global_load_lds((gv_t*)g, (lv_t*)l, 16, 0, 0);
}

// Frag-major layouts (so every attn load is base + lane*16B, coalesced):
//  Q/K:  X[bh][tile=i>>5][ks=hd>>4][l=hi*32+lq][j]  elem = T[i][hd]
//  QP/KP: same but outer index h
//  V:    V[bh][tile][c=dblk*2+ps][l][j]             elem = V[i][hd]

// ------------------------------------------------- fp32 -> bf16 convert (x)
__global__ __launch_bounds__(256) void cvt_x(const float* __restrict__ in,
                                             unsigned short* __restrict__ out) {
    int i = blockIdx.x * 256 + threadIdx.x;   // 1M threads, 4 floats each
    f32x4 v = *(const f32x4*)(in + i * 4);
    u16x4 o;
    o[0] = f2bf(v[0]); o[1] = f2bf(v[1]); o[2] = f2bf(v[2]); o[3] = f2bf(v[3]);
    *(u16x4*)(out + i * 4) = o;
}

// ------------------------------------- transpose fp32 in -> bf16 out (RxC)
__global__ __launch_bounds__(256) void transpose_cvt(
    const float* __restrict__ in, unsigned short* __restrict__ out,
    int R, int C) {
    __shared__ unsigned short tile[32][33];
    int c0 = blockIdx.x * 32, r0 = blockIdx.y * 32;
    int tx = threadIdx.x & 31, ty = threadIdx.x >> 5;
#pragma unroll
    for (int i = 0; i < 32; i += 8)
        tile[ty + i][tx] = f2bf(in[(r0 + ty + i) * C + c0 + tx]);
    __syncthreads();
#pragma unroll
    for (int i = 0; i < 32; i += 8)
        out[(c0 + ty + i) * R + r0 + tx] = tile[tx][ty + i];
}

// ---------- pos GEMM (pe computed in-kernel): pe(512x64)@w(64x2048),
// scattered to frag-major qpx/kpx; qp pre-scaled by log2(e)
__global__ __launch_bounds__(256) void posg(
    const float* __restrict__ w, unsigned short* __restrict__ qpx,
    unsigned short* __restrict__ kpx) {
    __shared__ float peS[64][64];
    __shared__ float wS[64][32];
    int c0 = blockIdx.x * 32, i0 = blockIdx.y * 64;
    int t = threadIdx.x;
#pragma unroll
    for (int j = 0; j < 16; ++j) {
        int o = t + j * 256;                 // 4096 = 64 rows x 64 cols
        int ri = o >> 6, d = o & 63, dd = d & 31;
        float inv = expf((float)dd * -0.2971077539347156f);  // -ln(1e4)/31
        float ang = (float)(i0 + ri - 256) * inv;
        peS[ri][d] = (d < 32) ? sinf(ang) : cosf(ang);
    }
#pragma unroll
    for (int j = 0; j < 8; ++j) {
        int o = t + j * 256;
        wS[o >> 5][o & 31] = w[(o >> 5) * 2048 + c0 + (o & 31)];
    }
    __syncthreads();
#pragma unroll
    for (int j = 0; j < 8; ++j) {
        int o = t + j * 256;
        int row = o >> 5, col = o & 31;
        float acc = 0.0f;
#pragma unroll
        for (int k = 0; k < 64; ++k) acc += peS[row][k] * wS[k][col];
        int c = c0 + col, i = i0 + row;
        int qt = i >> 5, lq = i & 31;
        int cc = (c < 1024) ? c : (c - 1024);
        int h = cc >> 6, kk = cc & 63;
        int ks = kk >> 4, h2 = (kk >> 3) & 1, jj = kk & 7;
        unsigned idx = ((unsigned)(h * 4096 + qt * 256 + ks * 64 + h2 * 32 + lq)
                        << 3) + jj;
        if (c < 1024) qpx[idx] = f2bf(acc * LOG2E);
        else          kpx[idx] = f2bf(acc);
    }
}

// ---------------------------------------------------------------- GEMM
// C = A(MxK bf16 rm) x Bt(NxK bf16 rm)^T. 128x128 tile, BK=32, DOUBLE-
// BUFFERED LDS (2x16KB) + counted vmcnt + raw barriers (T4): loads for
// tile k+2 stay in flight across barriers; vmcnt never drains to 0 in the
// main loop. Bank swizzle: LDS[row][c] holds chunk c ^ ((row>>1)&3) via
// pre-swizzled gload SOURCE (dest linear, rule 21) + XOR on ds_read.
// MODE 0: scatter bf16 to frag-major q(*log2e), k, v. MODE 1: fp32 +bias.
template <int MODE>
__global__ __launch_bounds__(256) void gemm_bt(
    const unsigned short* __restrict__ A, const unsigned short* __restrict__ Bt,
    int M, int N, int K, int NBX, unsigned short* __restrict__ o0,
    unsigned short* __restrict__ o1, unsigned short* __restrict__ o2,
    float* __restrict__ fout, const float* __restrict__ bias) {
    __shared__ __align__(16) unsigned short As[2][128 * 32];   // 2 x 8KB
    __shared__ __align__(16) unsigned short Bs[2][128 * 32];
    int g = blockIdx.x;
    int swz = (g & 7) * (gridDim.x >> 3) + (g >> 3);   // XCD-contiguous chunks
    int bx = swz % NBX, by = swz / NBX;
    int m0 = by * 128, n0 = bx * 128;
    int t = threadIdx.x;
    int w = t >> 6, l = t & 63, lg = l >> 4, lc = l & 15;
    int wr = w >> 1, wc = w & 1;

    f32x4 acc[4][4] = {};

    int sr = t >> 2;                        // staging row 0..63 (and +64)
    int sc = (t & 3) ^ ((t >> 3) & 3);      // swizzled chunk, f(row)=(row>>1)&3
    const unsigned short* Ab = A + (m0 + sr) * K + sc * 8;
    const unsigned short* Bb = Bt + (n0 + sr) * K + sc * 8;
    int rsw = (lc >> 1) & 3;                // read-side f(row)

    auto stage = [&](int buf, int k0) {
        gload16(Ab + k0, &As[buf][w * 512]);
        gload16(Ab + 64 * K + k0, &As[buf][2048 + w * 512]);
        gload16(Bb + k0, &Bs[buf][w * 512]);
        gload16(Bb + 64 * K + k0, &Bs[buf][2048 + w * 512]);
    };

    stage(0, 0);                            // 2-deep prologue
    stage(1, 32);
    int cur = 0;
    for (int k0 = 0; k0 < K; k0 += 32) {
        // wait for buf[cur]'s 4 loads; keep the other buffer's 4 in flight
        if (k0 + 32 < K)
            asm volatile("s_waitcnt vmcnt(4)" ::: "memory");
        else
            asm volatile("s_waitcnt vmcnt(0)" ::: "memory");
        __builtin_amdgcn_sched_barrier(0);
        __builtin_amdgcn_s_barrier();       // all waves' cur-loads landed
        __builtin_amdgcn_sched_barrier(0);
        u16x8 af[4], bf[4];
#pragma unroll
        for (int mm = 0; mm < 4; ++mm)
            af[mm] = *(const u16x8*)&As[cur][(wr * 64 + mm * 16 + lc) * 32 +
                                             ((lg ^ rsw) << 3)];
#pragma unroll
        for (int nn = 0; nn < 4; ++nn)
            bf[nn] = *(const u16x8*)&Bs[cur][(wc * 64 + nn * 16 + lc) * 32 +
                                             ((lg ^ rsw) << 3)];
        asm volatile("s_waitcnt lgkmcnt(0)" ::: "memory");
        __builtin_amdgcn_sched_barrier(0);
        __builtin_amdgcn_s_barrier();       // all waves done reading cur
        __builtin_amdgcn_sched_barrier(0);
        if (k0 + 64 < K) stage(cur, k0 + 64);   // overwrite cur with k+2
#pragma unroll
        for (int mm = 0; mm < 4; ++mm)
#pragma unroll
            for (int nn = 0; nn < 4; ++nn)
                acc[mm][nn] = mfma16(af[mm], bf[nn], acc[mm][nn]);
        cur ^= 1;
    }

#pragma unroll
    for (int mm = 0; mm < 4; ++mm)
#pragma unroll
        for (int nn = 0; nn < 4; ++nn)
#pragma unroll
            for (int r = 0; r < 4; ++r) {
                int row = m0 + wr * 64 + mm * 16 + lg * 4 + r;
                int col = n0 + wc * 64 + nn * 16 + lc;
                float v = acc[mm][nn][r];
                if (MODE == 0) {
                    int bb = row >> 9, i = row & 511;
                    int which = col >> 10, dd = col & 1023;
                    int hh = dd >> 6, hd = dd & 63;
                    int bh2 = bb * HH + hh;
                    int tl = i >> 5, io = i & 31;
                    if (which == 2) {       // V frag-major
                        int h2 = (io >> 2) & 1, ps = (io >> 4) & 1;
                        int j = (io & 3) | (((io >> 3) & 1) << 2);
                        int dblk = hd >> 5, lq = hd & 31;
                        unsigned idx = ((unsigned)(bh2 * 4096 + tl * 256 +
                                        (dblk * 2 + ps) * 64 + h2 * 32 + lq)
                                        << 3) + j;
                        o2[idx] = f2bf(v);
                    } else {                // Q/K frag-major
                        int ks = hd >> 4, h2 = (hd >> 3) & 1, j = hd & 7;
                        unsigned idx = ((unsigned)(bh2 * 4096 + tl * 256 +
                                        ks * 64 + h2 * 32 + io) << 3) + j;
                        if (which == 0) o0[idx] = f2bf(v * LOG2E);
                        else            o1[idx] = f2bf(v);
                    }
                } else {
                    fout[row * N + col] = v + bias[col];
                }
            }
}

// ---------------------------------------------------------------- attention
// Swapped-QK^T + 2-way key split, frag-major (coalesced) inputs. Fully
// unrolled tile loop, early V-load issue, no barriers/LDS in the loop.
__global__ void attn_k(
    const unsigned short* __restrict__ Qx, const unsigned short* __restrict__ Kx,
    const unsigned short* __restrict__ Vx, const unsigned short* __restrict__ QPx,
    const unsigned short* __restrict__ KPx, const int* __restrict__ mask,
    const int* __restrict__ qmask, const float* __restrict__ shp,
    unsigned short* __restrict__ out) {
    __shared__ float mbuf[2][64];
    __shared__ float lsbuf[2][64];
    __shared__ float obuf[2][64][33];          // +1 pad: conflict-free

    int g = blockIdx.x;                        // 1024 blocks
    int bid = ((g & 7) << 7) + (g >> 3);       // one batch per XCD
    int b = bid >> 7, h = (bid >> 3) & 15, qc = bid & 7;
    int t = threadIdx.x, w = t >> 6, l = t & 63;
    int qg = w & 1, kh = w >> 1;               // q-group, key-half
    int lq = l & 31, hi = l >> 5;
    int q = qc * 64 + qg * 32 + lq;            // this lane's q-row
    int bh = b * HH + h;
    int qt = qc * 2 + qg;                      // q 32-tile index

    // coalesced frag-major prologue loads (lane l -> +l*16B)
    const unsigned short* qb  = Qx  + (((unsigned)(bh * 4096 + qt * 256)) << 3) + (l << 3);
    const unsigned short* qpb = QPx + (((unsigned)(h  * 4096 + qt * 256)) << 3) + (l << 3);
    u16x8 qf[4], pf[4];
#pragma unroll
    for (int ks = 0; ks < 4; ++ks) {
        qf[ks] = *(const u16x8*)(qb + ks * 512);
        pf[ks] = *(const u16x8*)(qpb + ks * 512);
    }

    // ballot-packed key masks for THIS key half (256 bits, wave-uniform)
    unsigned long long km[4], qm[4];
#pragma unroll
    for (int t8 = 0; t8 < 4; ++t8) {
        int base = b * LL + (kh * 4 + t8) * 64 + l;
        km[t8] = __ballot(mask[base] != 0);
        qm[t8] = __ballot(qmask[base] != 0);
    }
    int qi = (qmask[b * LL + q] != 0) ? 1 : 0;

    const float M0 = -1.0e30f, NEGF = -3.0e38f, THR = 8.0f;
    float negs = -(*shp) * LOG2E;
    float m = M0, ls = 0.0f;
    f32x16 o0 = {}, o1 = {};
    float fq = (float)(q - 4 * hi);

#pragma unroll
    for (int tt = 0; tt < 8; ++tt) {
        int ttg = kh * 8 + tt;                 // global 32-key tile index
        // ---- issue ALL of this tile's loads first (K, KP, V coalesced)
        const unsigned short* kb  = Kx  + (((unsigned)(bh * 4096 + ttg * 256)) << 3) + (l << 3);
        const unsigned short* kpb = KPx + (((unsigned)(h  * 4096 + ttg * 256)) << 3) + (l << 3);
        const unsigned short* vb  = Vx  + (((unsigned)(bh * 4096 + ttg * 256)) << 3) + (l << 3);
        u16x8 vf0 = *(const u16x8*)(vb);
        u16x8 vf1 = *(const u16x8*)(vb + 512);
        u16x8 vf2 = *(const u16x8*)(vb + 1024);
        u16x8 vf3 = *(const u16x8*)(vb + 1536);
        // ---- S^T tile: two independent 4-deep MFMA chains
        f32x16 sk = {}, sp = {};
#pragma unroll
        for (int ks = 0; ks < 4; ++ks) {
            sk = mfma32(*(const u16x8*)(kb + ks * 512), qf[ks], sk);
            sp = mfma32(*(const u16x8*)(kpb + ks * 512), pf[ks], sp);
        }

        // ---- masks + gaussian (log2 domain)
        unsigned kwn = ((unsigned)(km[tt >> 1] >> ((tt & 1) * 32))) >> (hi * 4);
        unsigned qwn = ((unsigned)(qm[tt >> 1] >> ((tt & 1) * 32))) >> (hi * 4);
        float bt = fq - 32.0f * (float)ttg;
        float p[16];
#pragma unroll
        for (int r = 0; r < 16; ++r) {
            const int off = (r & 3) + 8 * (r >> 2);   // key row within tile
            float v = sk[r] + sp[r];
            v = (((qwn >> off) & 1u) == (unsigned)qi) ? v : 0.0f;
            float dr = bt - (float)off;
            v = __builtin_fmaf(negs * dr, dr, v);
            v = ((kwn >> off) & 1u) ? v : NEGF;
            p[r] = v;
        }
        // ---- row max over tile (in-lane tree + cross-half shfl)
        float a0 = fmaxf(fmaxf(p[0], p[1]), fmaxf(p[2], p[3]));
        float a1 = fmaxf(fmaxf(p[4], p[5]), fmaxf(p[6], p[7]));
        float a2 = fmaxf(fmaxf(p[8], p[9]), fmaxf(p[10], p[11]));
        float a3 = fmaxf(fmaxf(p[12], p[13]), fmaxf(p[14], p[15]));
        float pmax = fmaxf(fmaxf(a0, a1), fmaxf(a2, a3));
        pmax = fmaxf(pmax, __shfl_xor(pmax, 32));
        // ---- defer-max rescale (wave-uniform branch, per-lane m)
        if (!__all(pmax <= m + THR)) {
            float mn = fmaxf(m, pmax);
            float sc = __builtin_amdgcn_exp2f(m - mn);
#pragma unroll
            for (int r = 0; r < 16; ++r) { o0[r] *= sc; o1[r] *= sc; }
            ls *= sc;
            m = mn;
        }
        // ---- P = exp2(s - m) (<= 2^THR), partial row-sum
#pragma unroll
        for (int r = 0; r < 16; ++r) p[r] = __builtin_amdgcn_exp2f(p[r] - m);
        ls += (((p[0] + p[1]) + (p[2] + p[3])) + ((p[4] + p[5]) + (p[6] + p[7]))) +
              (((p[8] + p[9]) + (p[10] + p[11])) +
               ((p[12] + p[13]) + (p[14] + p[15])));
        // ---- PV slot-paired with frag-major V
        u16x8 pf0, pf1;
#pragma unroll
        for (int j = 0; j < 8; ++j) { pf0[j] = f2bf(p[j]); pf1[j] = f2bf(p[8 + j]); }
        o0 = mfma32(vf0, pf0, o0);
        o0 = mfma32(vf1, pf1, o0);
        o1 = mfma32(vf2, pf0, o1);
        o1 = mfma32(vf3, pf1, o1);
    }

    // ---- flash-combine the two key halves via LDS
    if (kh == 1) {
        mbuf[qg][l] = m;
        lsbuf[qg][l] = ls;
#pragma unroll
        for (int r = 0; r < 16; ++r) {
            obuf[qg][l][r] = o0[r];
            obuf[qg][l][16 + r] = o1[r];
        }
    }
    __syncthreads();
    if (kh == 0) {
        float m1 = mbuf[qg][l], ls1 = lsbuf[qg][l];
        float mm = fmaxf(m, m1);
        float sc0 = __builtin_amdgcn_exp2f(m - mm);
        float sc1 = __builtin_amdgcn_exp2f(m1 - mm);
        float lsm = ls * sc0 + ls1 * sc1;
        float rs = lsm + __shfl_xor(lsm, 32);
        float rinv = __builtin_amdgcn_rcpf(rs);       // rs >= 1
        unsigned short* ob = out + ((long)(b * LL + q)) * DD + h * HD + hi * 4;
#pragma unroll
        for (int rg = 0; rg < 4; ++rg) {
            u16x4 pk0, pk1;
#pragma unroll
            for (int rr = 0; rr < 4; ++rr) {
                int i = rg * 4 + rr;
                float v0 = __builtin_fmaf(o0[i], sc0, obuf[qg][l][i] * sc1);
                float v1 = __builtin_fmaf(o1[i], sc0, obuf[qg][l][16 + i] * sc1);
                pk0[rr] = f2bf(v0 * rinv);            // d = hi*4 + rg*8 + rr
                pk1[rr] = f2bf(v1 * rinv);
            }
            *(u16x4*)(ob + rg * 8) = pk0;
            *(u16x4*)(ob + 32 + rg * 8) = pk1;
        }
    }
}

// ---------------------------------------------------------------- launch
extern "C" void kernel_launch(void* const* d_in, const int* in_sizes, int n_in,
                              void* d_out, int out_size, void* d_ws,
                              size_t ws_size, hipStream_t stream) {
    const float* x     = (const float*)d_in[0];
    const int*   mask  = (const int*)d_in[1];
    const int*   qmask = (const int*)d_in[2];
    const float* w_qkv = (const float*)d_in[3];
    const float* w_qkp = (const float*)d_in[4];
    const float* w_fc  = (const float*)d_in[5];
    const float* b_fc  = (const float*)d_in[6];
    const float* shift = (const float*)d_in[7];
    // d_in[8] (bias) cancels in softmax — unused

    char* ws = (char*)d_ws;
    unsigned short* xb   = (unsigned short*)(ws);              //  8 MB bf16 x
    unsigned short* qb   = (unsigned short*)(ws + 8388608);    //  8 MB frag-major Q
    unsigned short* kb   = (unsigned short*)(ws + 16777216);   //  8 MB frag-major K
    unsigned short* vtb  = (unsigned short*)(ws + 25165824);   //  8 MB frag-major V
    unsigned short* qp   = (unsigned short*)(ws + 33554432);   //  1 MB frag-major QP
    unsigned short* kp   = (unsigned short*)(ws + 34603008);   //  1 MB frag-major KP
    unsigned short* wqt  = (unsigned short*)(ws + 35651584);   //  6 MB (3D,D)
    unsigned short* wft  = (unsigned short*)(ws + 41943040);   //  2 MB (D,D)
    unsigned short* aout = (unsigned short*)(ws + 44040192);   //  8 MB (B,L,D)

    cvt_x<<<4096, 256, 0, stream>>>(x, xb);
    transpose_cvt<<<dim3(96, 32), 256, 0, stream>>>(w_qkv, wqt, 1024, 3072);
    transpose_cvt<<<dim3(32, 32), 256, 0, stream>>>(w_fc, wft, 1024, 1024);
    posg<<<dim3(64, 8), 256, 0, stream>>>(w_qkp, qp, kp);
    gemm_bt<0><<<768, 256, 0, stream>>>(xb, wqt, 4096, 3072, 1024, 24, qb, kb,
                                        vtb, nullptr, nullptr);
    attn_k<<<1024, 256, 0, stream>>>(qb, kb, vtb, qp, kp, mask, qmask, shift,
                                     aout);
    gemm_bt<1><<<256, 256, 0, stream>>>(aout, wft, 4096, 1024, 1024, 8, nullptr,
                                        nullptr, nullptr, (float*)d_out, b_fc);
}